// Round 16
// baseline (319.913 us; speedup 1.0000x reference)
//
#include <hip/hip_runtime.h>

// out[b,c,y,x] = sum_{kdy,kdx in [0,9)} corr[b, kdy*9+kdx, y+4-kdy, x+4-kdx] * feat[b,c, y+4-kdy, x+4-kdx]
// R16: barrier-free streaming MFMA. Prepass1: feat->bf16 (featb). Prepass2: corr->banded
// slices mband[(b*96+sy)*9+kdy][x][o] = corr[b,kdy*9+(x+8-(kb+o)),sy,kb+o-4] (0 out-of-band),
// kb(x) = x<80 ? x&~15 : 72. Main: per (b,y,ch-half) block, 4 waves x 32ch, NO LDS:
// A/B MFMA fragments loaded directly from featb/mband (16B/lane, coalesced, L1/L2-hot).

#define RR 4
#define DD 9
#define D2 81
#define Bn 16
#define Cn 256
#define Hn 96
#define Wn 96
#define HWn (Hn*Wn)
#define MW  32

typedef __attribute__((ext_vector_type(8))) short bf16x8;
typedef __attribute__((ext_vector_type(4))) float f32x4;

__device__ __forceinline__ uint cvt_pk(float lo, float hi) {
    uint r;
    asm("v_cvt_pk_bf16_f32 %0, %1, %2" : "=v"(r) : "v"(lo), "v"(hi));
    return r;
}
__device__ __forceinline__ ushort f2bf(float f) {
    uint u = __float_as_uint(f);
    return (ushort)((u + 0x7FFFu + ((u >> 16) & 1u)) >> 16);
}

// ---- prepass 1: feat fp32 -> bf16 ----
__global__ void prep_feat_kernel(const float* __restrict__ feat, ushort* __restrict__ featb)
{
    const int n8 = Bn * Cn * HWn / 8;
    const float4* src = reinterpret_cast<const float4*>(feat);
    uint4* dst = reinterpret_cast<uint4*>(featb);
    for (int i = blockIdx.x * blockDim.x + threadIdx.x; i < n8; i += gridDim.x * blockDim.x) {
        float4 a = src[2 * i], c = src[2 * i + 1];
        dst[i] = make_uint4(cvt_pk(a.x, a.y), cvt_pk(a.z, a.w), cvt_pk(c.x, c.y), cvt_pk(c.z, c.w));
    }
}

// ---- prepass 2: corr -> banded M slices, one block per (b,sy), uint4 writes ----
__global__ __launch_bounds__(384)
void prep_mband_kernel(const float* __restrict__ corr, ushort* __restrict__ mband)
{
    const int s  = blockIdx.x;               // b*Hn + sy
    const int sy = s % Hn, b = s / Hn;
    const float* cb = corr + (size_t)b * D2 * HWn + (size_t)sy * Wn;
    const int t   = threadIdx.x;             // 384 = 96 x * 4 octets
    const int x   = t >> 2, oct = t & 3;
    const int kb  = (x >= 80) ? 72 : (x & ~15);
    ushort* mbase = mband + ((size_t)s * DD) * (Wn * MW) + x * MW + oct * 8;
    #pragma unroll 1
    for (int kdy = 0; kdy < DD; ++kdy) {
        ushort v[8];
        #pragma unroll
        for (int i = 0; i < 8; ++i) {
            int o   = oct * 8 + i;
            int sxp = kb + o;
            int kdx = x + 2 * RR - sxp;
            float f = 0.f;
            if (kdx >= 0 && kdx < DD && sxp >= RR && sxp < Wn + RR)
                f = cb[(size_t)(kdy * DD + kdx) * HWn + (sxp - RR)];
            v[i] = f2bf(f);
        }
        *reinterpret_cast<uint4*>(mbase + (size_t)kdy * (Wn * MW)) =
            make_uint4((uint)v[0] | ((uint)v[1] << 16), (uint)v[2] | ((uint)v[3] << 16),
                       (uint)v[4] | ((uint)v[5] << 16), (uint)v[6] | ((uint)v[7] << 16));
    }
}

// ---- main: barrier-free, LDS-free streaming MFMA ----
__global__ __launch_bounds__(256, 4)
void corrT16_kernel(const ushort* __restrict__ featb, const ushort* __restrict__ mband,
                    float* __restrict__ out)
{
    // XCD-chunked: y contiguous per XCD, ch-half innermost. grid 3072 = 8 * 384.
    int bid = blockIdx.x;
    int local = bid >> 3;                    // 0..383
    int cgh = local & 1;
    int r2  = local >> 1;                    // 0..191
    int y   = r2 % Hn;
    int b   = (bid & 7) * 2 + r2 / Hn;

    const int tid  = threadIdx.x;
    const int lane = tid & 63;
    const int wid  = tid >> 6;               // 4 waves x 32 ch
    const int mrow = lane & 15;
    const int kq   = lane >> 4;
    const int kgrp = kq << 3;
    const int c0   = cgh * 128 + wid * 32;

    const int klo = max(0, y - (Hn - 1 - RR));
    const int khi = min(DD - 1, y + RR);

    const ushort* arow0 = featb + (((size_t)b * Cn + c0 + mrow) * Hn) * Wn;
    const ushort* arow1 = arow0 + (size_t)16 * HWn;

    f32x4 acc0[6], acc1[6];
    #pragma unroll
    for (int t6 = 0; t6 < 6; ++t6) {
        acc0[t6] = (f32x4){0.f, 0.f, 0.f, 0.f};
        acc1[t6] = (f32x4){0.f, 0.f, 0.f, 0.f};
    }

    #pragma unroll 1
    for (int kk = klo; kk <= khi; ++kk) {
        const int sy = y + RR - kk;
        const ushort* a0 = arow0 + (size_t)sy * Wn;
        const ushort* a1 = arow1 + (size_t)sy * Wn;
        const ushort* ms = mband + (((size_t)b * Hn + sy) * DD + kk) * (size_t)(Wn * MW)
                           + mrow * MW + kgrp;
        #pragma unroll
        for (int t6 = 0; t6 < 6; ++t6) {
            uint4 mwv = *reinterpret_cast<const uint4*>(ms + t6 * 16 * MW);
            uint4 av0, av1;
            if (t6 == 0) {
                // need A[sxp=kgrp..+8]; A[sxp]=feat[sxp-4], pad sxp<4 -> shuffle for kq==0
                const int col = (kq == 0) ? 0 : (kgrp - 4);
                uint4 L0 = *reinterpret_cast<const uint4*>(a0 + col);
                uint4 L1 = *reinterpret_cast<const uint4*>(a1 + col);
                av0 = (kq == 0) ? make_uint4(0u, 0u, L0.x, L0.y) : L0;
                av1 = (kq == 0) ? make_uint4(0u, 0u, L1.x, L1.y) : L1;
            } else if (t6 == 5) {
                // sxp = 72+kgrp..+8; pad sxp>=100 -> shuffle for kq==3
                const int col = (kq == 3) ? 88 : (72 + kgrp - 4);
                uint4 L0 = *reinterpret_cast<const uint4*>(a0 + col);
                uint4 L1 = *reinterpret_cast<const uint4*>(a1 + col);
                av0 = (kq == 3) ? make_uint4(L0.z, L0.w, 0u, 0u) : L0;
                av1 = (kq == 3) ? make_uint4(L1.z, L1.w, 0u, 0u) : L1;
            } else {
                const int col = t6 * 16 + kgrp - 4;
                av0 = *reinterpret_cast<const uint4*>(a0 + col);
                av1 = *reinterpret_cast<const uint4*>(a1 + col);
            }
            bf16x8 bfr = *reinterpret_cast<bf16x8*>(&mwv);
            bf16x8 af0 = *reinterpret_cast<bf16x8*>(&av0);
            bf16x8 af1 = *reinterpret_cast<bf16x8*>(&av1);
            acc0[t6] = __builtin_amdgcn_mfma_f32_16x16x32_bf16(af0, bfr, acc0[t6], 0, 0, 0);
            acc1[t6] = __builtin_amdgcn_mfma_f32_16x16x32_bf16(af1, bfr, acc1[t6], 0, 0, 0);
        }
    }

    // epilogue: C/D layout col=lane&15 (x), row=(lane>>4)*4+r (c) — R11/R15-verified
    const int csub = kq << 2;
    #pragma unroll
    for (int t6 = 0; t6 < 6; ++t6) {
        #pragma unroll
        for (int r = 0; r < 4; ++r) {
            out[(((size_t)b * Cn + c0 + csub + r) * Hn + y) * Wn + t6 * 16 + mrow] = acc0[t6][r];
            out[(((size_t)b * Cn + c0 + 16 + csub + r) * Hn + y) * Wn + t6 * 16 + mrow] = acc1[t6][r];
        }
    }
}

// ---- fallback (ws too small): proven R8 fp32 scalar kernel ----
#define NTXf 12
#define NTCf 32
#define NTHf (NTXf*NTCf)
#define LWf  100
#define LW4f (LWf/4)
__global__ __launch_bounds__(NTHf, 6)
void corrT8_kernel(const float* __restrict__ corr, const float* __restrict__ feat,
                   float* __restrict__ out)
{
    __shared__ float lds[D2 * LWf];
    int bid = blockIdx.x;
    int sw  = (bid & 7) * (gridDim.x >> 3) + (bid >> 3);
    int cg  = sw & 3;
    int y   = (sw >> 2) % Hn;
    int b   = sw / (4 * Hn);
    const int tid = threadIdx.x;
    const float* corrb = corr + (size_t)b * D2 * HWn;
    for (int idx = tid; idx < D2 * LW4f; idx += NTHf) {
        int row = idx / LW4f, c4 = idx - row * LW4f;
        int kdy = row / DD, kdx = row - kdy * DD;
        int sy  = y + RR - kdy;
        float4 v = make_float4(0.f, 0.f, 0.f, 0.f);
        if (sy >= 0 && sy < Hn) {
            const float* src = corrb + (size_t)row * HWn + sy * Wn;
            #pragma unroll
            for (int e = 0; e < 4; ++e) {
                int sx = c4 * 4 + e - kdx;
                if (sx >= 0 && sx < Wn) (&v.x)[e] = src[sx];
            }
        }
        *reinterpret_cast<float4*>(&lds[row * LWf + c4 * 4]) = v;
    }
    __syncthreads();
    const int tx = tid % NTXf, tc = tid / NTXf;
    const int x0 = tx * 8, c0 = cg * 64 + tc * 2;
    const float* featb2 = feat + ((size_t)b * Cn + c0) * HWn;
    float acc[2][8] = {};
    const int klo = max(0, y - (Hn - 1 - RR)), khi = min(DD - 1, y + RR);
    #pragma unroll 1
    for (int kdy = klo; kdy <= khi; ++kdy) {
        int sy = y + RR - kdy;
        float f[2][16];
        const float* frow = featb2 + sy * Wn + x0 - RR;
        #pragma unroll
        for (int c = 0; c < 2; ++c) {
            const float* p = frow + (size_t)c * HWn;
            float4 f0 = (tx == 0) ? make_float4(0,0,0,0) : *reinterpret_cast<const float4*>(p);
            float4 f1 = *reinterpret_cast<const float4*>(p + 4);
            float4 f2 = *reinterpret_cast<const float4*>(p + 8);
            float4 f3 = (tx == NTXf-1) ? make_float4(0,0,0,0) : *reinterpret_cast<const float4*>(p + 12);
            f[c][0]=f0.x; f[c][1]=f0.y; f[c][2]=f0.z; f[c][3]=f0.w;
            f[c][4]=f1.x; f[c][5]=f1.y; f[c][6]=f1.z; f[c][7]=f1.w;
            f[c][8]=f2.x; f[c][9]=f2.y; f[c][10]=f2.z; f[c][11]=f2.w;
            f[c][12]=f3.x; f[c][13]=f3.y; f[c][14]=f3.z; f[c][15]=f3.w;
        }
        const float4* base = reinterpret_cast<const float4*>(lds) + (tx * 2 + 1) + kdy * DD * LW4f;
        float4 ca = base[0], cb = base[1];
        #pragma unroll
        for (int kdx = 0; kdx < DD; ++kdx) {
            float4 na = ca, nb = cb;
            if (kdx < DD - 1) { na = base[(kdx+1)*LW4f]; nb = base[(kdx+1)*LW4f + 1]; }
            float cv[8] = {ca.x, ca.y, ca.z, ca.w, cb.x, cb.y, cb.z, cb.w};
            #pragma unroll
            for (int c = 0; c < 2; ++c)
                #pragma unroll
                for (int j = 0; j < 8; ++j)
                    acc[c][j] = fmaf(cv[j], f[c][j + 8 - kdx], acc[c][j]);
            ca = na; cb = nb;
        }
    }
    float* ob = out + ((size_t)b * Cn + c0) * HWn + (size_t)y * Wn + x0;
    #pragma unroll
    for (int c = 0; c < 2; ++c) {
        *reinterpret_cast<float4*>(ob + (size_t)c * HWn)     = make_float4(acc[c][0], acc[c][1], acc[c][2], acc[c][3]);
        *reinterpret_cast<float4*>(ob + (size_t)c * HWn + 4) = make_float4(acc[c][4], acc[c][5], acc[c][6], acc[c][7]);
    }
}

extern "C" void kernel_launch(void* const* d_in, const int* in_sizes, int n_in,
                              void* d_out, int out_size, void* d_ws, size_t ws_size,
                              hipStream_t stream)
{
    const float* corr = (const float*)d_in[0];   // [16,81,96,96]
    const float* feat = (const float*)d_in[1];   // [16,256,96,96]
    float* out = (float*)d_out;                  // [16,256,96,96]

    const size_t needF = (size_t)Bn * Cn * HWn * 2;              // 75,497,472
    const size_t needM = (size_t)Bn * Hn * DD * Wn * MW * 2;     // 84,934,656

    if (ws_size >= needF + needM) {
        ushort* featb = (ushort*)d_ws;
        ushort* mband = (ushort*)((char*)d_ws + needF);
        prep_feat_kernel<<<4096, 256, 0, stream>>>(feat, featb);
        prep_mband_kernel<<<Bn * Hn, 384, 0, stream>>>(corr, mband);
        corrT16_kernel<<<Bn * Hn * 2, 256, 0, stream>>>(featb, mband, out);
    } else {
        corrT8_kernel<<<Bn * Hn * 4, NTHf, 0, stream>>>(corr, feat, out);
    }
}

// Round 17
// 193.710 us; speedup vs baseline: 1.6515x; 1.6515x over previous
//
#include <hip/hip_runtime.h>

// out[b,c,y,x] = sum_{kdy,kdx in [0,9)} corr[b, kdy*9+kdx, y+4-kdy, x+4-kdx] * feat[b,c, y+4-kdy, x+4-kdx]
// R17 = R15's measured-best main (111us: A_sh single-buf + M_sh dbuf, T14 issue-early/
// write-late, 2 blocks/CU) + R16's verified vectorized prepasses (uint4 mband writes,
// one block per (b,sy) for corr-row reuse).
//   featb[b,c,sy,sx] = bf16(feat)            (prepass 1)
//   mband[(b*96+sy)*9+kdy][x][o] = bf16(corr[b, kdy*9+(x+8-(kb+o)), sy, kb+o-4]), 0 OOB,
//     kb(x) = x<80 ? x&~15 : 72              (prepass 2, R11/R15-verified numerics)
//   main: per (b,y): out[C,X] = sum_kdy A[C,K=104-window] * M[K,X]  via 16x16x32 bf16 MFMA

#define RR 4
#define DD 9
#define D2 81
#define Bn 16
#define Cn 256
#define Hn 96
#define Wn 96
#define HWn (Hn*Wn)
#define NTH 512
#define KW  104           // A row width (ushort); 208B stride -> 2-way banks (free)
#define MW  32            // M window width; 64B stride -> aligned b128

typedef __attribute__((ext_vector_type(8))) short bf16x8;
typedef __attribute__((ext_vector_type(4))) float f32x4;

__device__ __forceinline__ uint cvt_pk(float lo, float hi) {
    uint r;
    asm("v_cvt_pk_bf16_f32 %0, %1, %2" : "=v"(r) : "v"(lo), "v"(hi));
    return r;
}
__device__ __forceinline__ ushort f2bf(float f) {
    uint u = __float_as_uint(f);
    return (ushort)((u + 0x7FFFu + ((u >> 16) & 1u)) >> 16);
}

// ---- prepass 1: feat fp32 -> bf16 (streaming, 227 MB total traffic) ----
__global__ void prep_feat_kernel(const float* __restrict__ feat, ushort* __restrict__ featb)
{
    const int n8 = Bn * Cn * HWn / 8;
    const float4* src = reinterpret_cast<const float4*>(feat);
    uint4* dst = reinterpret_cast<uint4*>(featb);
    for (int i = blockIdx.x * blockDim.x + threadIdx.x; i < n8; i += gridDim.x * blockDim.x) {
        float4 a = src[2 * i], c = src[2 * i + 1];
        dst[i] = make_uint4(cvt_pk(a.x, a.y), cvt_pk(a.z, a.w), cvt_pk(c.x, c.y), cvt_pk(c.z, c.w));
    }
}

// ---- prepass 2 (R16-verified): corr -> banded M slices, block per (b,sy), uint4 writes ----
__global__ __launch_bounds__(384)
void prep_mband_kernel(const float* __restrict__ corr, ushort* __restrict__ mband)
{
    const int s  = blockIdx.x;               // b*Hn + sy
    const int sy = s % Hn, b = s / Hn;
    const float* cb = corr + (size_t)b * D2 * HWn + (size_t)sy * Wn;
    const int t   = threadIdx.x;             // 384 = 96 x * 4 octets
    const int x   = t >> 2, oct = t & 3;
    const int kb  = (x >= 80) ? 72 : (x & ~15);
    ushort* mbase = mband + ((size_t)s * DD) * (Wn * MW) + x * MW + oct * 8;
    #pragma unroll 1
    for (int kdy = 0; kdy < DD; ++kdy) {
        ushort v[8];
        #pragma unroll
        for (int i = 0; i < 8; ++i) {
            int o   = oct * 8 + i;
            int sxp = kb + o;
            int kdx = x + 2 * RR - sxp;
            float f = 0.f;
            if (kdx >= 0 && kdx < DD && sxp >= RR && sxp < Wn + RR)
                f = cb[(size_t)(kdy * DD + kdx) * HWn + (sxp - RR)];
            v[i] = f2bf(f);
        }
        *reinterpret_cast<uint4*>(mbase + (size_t)kdy * (Wn * MW)) =
            make_uint4((uint)v[0] | ((uint)v[1] << 16), (uint)v[2] | ((uint)v[3] << 16),
                       (uint)v[4] | ((uint)v[5] << 16), (uint)v[6] | ((uint)v[7] << 16));
    }
}

// ---- main (R15 MODE-2, measured 111 us): 2 blocks/CU, T14 issue-early/write-late ----
__global__ __launch_bounds__(NTH, 2)
void corrT17_kernel(const ushort* __restrict__ featb, const ushort* __restrict__ mband,
                    float* __restrict__ out)
{
    __shared__ ushort A_sh[Cn][KW];        // 53248 B, single buffer
    __shared__ ushort M_sh[2][Wn][MW];     // 12288 B, double buffer (total 64 KB)

    // XCD-chunked dispatch: y contiguous per XCD (grid 1536 = 8*192)
    int bid = blockIdx.x;
    int L   = (bid & 7) * 192 + (bid >> 3);
    int y   = L % Hn;
    int b   = L / Hn;

    const int tid  = threadIdx.x;
    const int lane = tid & 63;
    const int wid  = tid >> 6;
    const int mrow = lane & 15;
    const int kq   = lane >> 4;
    const int kgrp = kq << 3;

    for (int i = tid; i < Cn; i += NTH) {  // zero A pads once
        *reinterpret_cast<uint2*>(&A_sh[i][0])   = make_uint2(0u, 0u);
        *reinterpret_cast<uint2*>(&A_sh[i][100]) = make_uint2(0u, 0u);
    }
    __syncthreads();

    const int klo = max(0, y - (Hn - 1 - RR));
    const int khi = min(DD - 1, y + RR);

    const int ac  = tid >> 1;             // 2 threads per channel row
    const int seg = tid & 1;              // 48-element half row
    const ushort* fb_base = featb + (((size_t)b * Cn + ac) * Hn) * (size_t)Wn + seg * 48;

    // ---- prologue: stage A + M for kdy = klo ----
    {
        const int sy = y + RR - klo;
        const uint4* src = reinterpret_cast<const uint4*>(fb_base + (size_t)sy * Wn);
        #pragma unroll
        for (int i = 0; i < 6; ++i) {
            uint4 v = src[i];
            uint2* d = reinterpret_cast<uint2*>(&A_sh[ac][4 + seg * 48 + i * 8]);
            d[0] = make_uint2(v.x, v.y);
            d[1] = make_uint2(v.z, v.w);
        }
        const ushort* ms = mband + (((size_t)b * Hn + sy) * DD + klo) * (size_t)(Wn * MW);
        if (tid < 384)
            reinterpret_cast<uint4*>(&M_sh[0][0][0])[tid] = reinterpret_cast<const uint4*>(ms)[tid];
    }
    __syncthreads();

    f32x4 acc[2][6];
    #pragma unroll
    for (int ct = 0; ct < 2; ++ct)
        #pragma unroll
        for (int t6 = 0; t6 < 6; ++t6)
            acc[ct][t6] = (f32x4){0.f, 0.f, 0.f, 0.f};

    #pragma unroll 1
    for (int kk = klo; kk <= khi; ++kk) {
        const int pb = (kk - klo) & 1;
        const bool vn = (kk + 1 <= khi);
        const int syn = y + RR - (kk + 1);

        // -- T14 issue-early: next A row + next M slice held in regs across MFMA --
        uint4 a0, a1, a2, a3, a4, a5;
        uint4 mvv = make_uint4(0u, 0u, 0u, 0u);
        if (vn) {
            const uint4* src = reinterpret_cast<const uint4*>(fb_base + (size_t)syn * Wn);
            a0 = src[0]; a1 = src[1]; a2 = src[2]; a3 = src[3]; a4 = src[4]; a5 = src[5];
            const ushort* ms = mband + (((size_t)b * Hn + syn) * DD + (kk + 1)) * (size_t)(Wn * MW);
            if (tid < 384) mvv = reinterpret_cast<const uint4*>(ms)[tid];
        }

        // -- MFMA phase: 12 x v_mfma_f32_16x16x32_bf16 per wave --
        #pragma unroll
        for (int t6 = 0; t6 < 6; ++t6) {
            const int kb = (t6 == 5) ? 72 : t6 * 16;
            uint4 bw = *reinterpret_cast<const uint4*>(&M_sh[pb][t6 * 16 + mrow][kgrp]);
            bf16x8 bfr = *reinterpret_cast<bf16x8*>(&bw);
            #pragma unroll
            for (int ct = 0; ct < 2; ++ct) {
                bf16x8 afr = *reinterpret_cast<const bf16x8*>(&A_sh[wid * 32 + ct * 16 + mrow][kb + kgrp]);
                acc[ct][t6] = __builtin_amdgcn_mfma_f32_16x16x32_bf16(afr, bfr, acc[ct][t6], 0, 0, 0);
            }
        }
        __syncthreads();                  // done reading A_sh / M_sh[pb]

        // -- write-late --
        if (vn) {
            uint2* d0 = reinterpret_cast<uint2*>(&A_sh[ac][4 + seg * 48]);
            d0[0] = make_uint2(a0.x, a0.y); d0[1] = make_uint2(a0.z, a0.w);
            d0[2] = make_uint2(a1.x, a1.y); d0[3] = make_uint2(a1.z, a1.w);
            d0[4] = make_uint2(a2.x, a2.y); d0[5] = make_uint2(a2.z, a2.w);
            d0[6] = make_uint2(a3.x, a3.y); d0[7] = make_uint2(a3.z, a3.w);
            d0[8] = make_uint2(a4.x, a4.y); d0[9] = make_uint2(a4.z, a4.w);
            d0[10] = make_uint2(a5.x, a5.y); d0[11] = make_uint2(a5.z, a5.w);
            if (tid < 384)
                reinterpret_cast<uint4*>(&M_sh[pb ^ 1][0][0])[tid] = mvv;
        }
        __syncthreads();
    }

    // ---- epilogue: C/D layout col=lane&15 (x), row=(lane>>4)*4+r (c) — R11/R15-verified ----
    const int csub = kq << 2;
    #pragma unroll
    for (int ct = 0; ct < 2; ++ct)
        #pragma unroll
        for (int t6 = 0; t6 < 6; ++t6)
            #pragma unroll
            for (int r = 0; r < 4; ++r)
                out[(((size_t)b * Cn + wid * 32 + ct * 16 + csub + r) * Hn + y) * Wn + t6 * 16 + mrow]
                    = acc[ct][t6][r];
}

// ---- fallback (ws too small): proven R8 fp32 scalar kernel ----
#define NTXf 12
#define NTCf 32
#define NTHf (NTXf*NTCf)
#define LWf  100
#define LW4f (LWf/4)
__global__ __launch_bounds__(NTHf, 6)
void corrT8_kernel(const float* __restrict__ corr, const float* __restrict__ feat,
                   float* __restrict__ out)
{
    __shared__ float lds[D2 * LWf];
    int bid = blockIdx.x;
    int sw  = (bid & 7) * (gridDim.x >> 3) + (bid >> 3);
    int cg  = sw & 3;
    int y   = (sw >> 2) % Hn;
    int b   = sw / (4 * Hn);
    const int tid = threadIdx.x;
    const float* corrb = corr + (size_t)b * D2 * HWn;
    for (int idx = tid; idx < D2 * LW4f; idx += NTHf) {
        int row = idx / LW4f, c4 = idx - row * LW4f;
        int kdy = row / DD, kdx = row - kdy * DD;
        int sy  = y + RR - kdy;
        float4 v = make_float4(0.f, 0.f, 0.f, 0.f);
        if (sy >= 0 && sy < Hn) {
            const float* src = corrb + (size_t)row * HWn + sy * Wn;
            #pragma unroll
            for (int e = 0; e < 4; ++e) {
                int sx = c4 * 4 + e - kdx;
                if (sx >= 0 && sx < Wn) (&v.x)[e] = src[sx];
            }
        }
        *reinterpret_cast<float4*>(&lds[row * LWf + c4 * 4]) = v;
    }
    __syncthreads();
    const int tx = tid % NTXf, tc = tid / NTXf;
    const int x0 = tx * 8, c0 = cg * 64 + tc * 2;
    const float* featp = feat + ((size_t)b * Cn + c0) * HWn;
    float acc[2][8] = {};
    const int klo = max(0, y - (Hn - 1 - RR)), khi = min(DD - 1, y + RR);
    #pragma unroll 1
    for (int kdy = klo; kdy <= khi; ++kdy) {
        int sy = y + RR - kdy;
        float f[2][16];
        const float* frow = featp + sy * Wn + x0 - RR;
        #pragma unroll
        for (int c = 0; c < 2; ++c) {
            const float* p = frow + (size_t)c * HWn;
            float4 f0 = (tx == 0) ? make_float4(0,0,0,0) : *reinterpret_cast<const float4*>(p);
            float4 f1 = *reinterpret_cast<const float4*>(p + 4);
            float4 f2 = *reinterpret_cast<const float4*>(p + 8);
            float4 f3 = (tx == NTXf-1) ? make_float4(0,0,0,0) : *reinterpret_cast<const float4*>(p + 12);
            f[c][0]=f0.x; f[c][1]=f0.y; f[c][2]=f0.z; f[c][3]=f0.w;
            f[c][4]=f1.x; f[c][5]=f1.y; f[c][6]=f1.z; f[c][7]=f1.w;
            f[c][8]=f2.x; f[c][9]=f2.y; f[c][10]=f2.z; f[c][11]=f2.w;
            f[c][12]=f3.x; f[c][13]=f3.y; f[c][14]=f3.z; f[c][15]=f3.w;
        }
        const float4* base = reinterpret_cast<const float4*>(lds) + (tx * 2 + 1) + kdy * DD * LW4f;
        float4 ca = base[0], cb = base[1];
        #pragma unroll
        for (int kdx = 0; kdx < DD; ++kdx) {
            float4 na = ca, nb = cb;
            if (kdx < DD - 1) { na = base[(kdx+1)*LW4f]; nb = base[(kdx+1)*LW4f + 1]; }
            float cv[8] = {ca.x, ca.y, ca.z, ca.w, cb.x, cb.y, cb.z, cb.w};
            #pragma unroll
            for (int c = 0; c < 2; ++c)
                #pragma unroll
                for (int j = 0; j < 8; ++j)
                    acc[c][j] = fmaf(cv[j], f[c][j + 8 - kdx], acc[c][j]);
            ca = na; cb = nb;
        }
    }
    float* ob = out + ((size_t)b * Cn + c0) * HWn + (size_t)y * Wn + x0;
    #pragma unroll
    for (int c = 0; c < 2; ++c) {
        *reinterpret_cast<float4*>(ob + (size_t)c * HWn)     = make_float4(acc[c][0], acc[c][1], acc[c][2], acc[c][3]);
        *reinterpret_cast<float4*>(ob + (size_t)c * HWn + 4) = make_float4(acc[c][4], acc[c][5], acc[c][6], acc[c][7]);
    }
}

extern "C" void kernel_launch(void* const* d_in, const int* in_sizes, int n_in,
                              void* d_out, int out_size, void* d_ws, size_t ws_size,
                              hipStream_t stream)
{
    const float* corr = (const float*)d_in[0];   // [16,81,96,96]
    const float* feat = (const float*)d_in[1];   // [16,256,96,96]
    float* out = (float*)d_out;                  // [16,256,96,96]

    const size_t needF = (size_t)Bn * Cn * HWn * 2;              // 75,497,472
    const size_t needM = (size_t)Bn * Hn * DD * Wn * MW * 2;     // 84,934,656

    if (ws_size >= needF + needM) {
        ushort* featb = (ushort*)d_ws;
        ushort* mband = (ushort*)((char*)d_ws + needF);
        prep_feat_kernel<<<4096, 256, 0, stream>>>(feat, featb);
        prep_mband_kernel<<<Bn * Hn, 384, 0, stream>>>(corr, mband);
        corrT17_kernel<<<Bn * Hn, NTH, 0, stream>>>(featb, mband, out);
    } else {
        corrT8_kernel<<<Bn * Hn * 4, NTHf, 0, stream>>>(corr, feat, out);
    }
}